// Round 2
// baseline (382.603 us; speedup 1.0000x reference)
//
#include <hip/hip_runtime.h>

#define N_ 4096

__device__ __forceinline__ float ssqrt(float a) {
  if (a == 0.f) return 0.f;
  return copysignf(sqrtf(fabsf(a) + 1e-5f), a);
}

// ---------------- K1: Gram for stage 1 ----------------
// G[s][b][h][d][e] = sum_{n in split s} Xq[d,n]*Xk[e,n]; also row sums of Xq, Xk.
__global__ __launch_bounds__(256) void k1_gram(const float* __restrict__ x,
    float* __restrict__ Gp, float* __restrict__ sxq, float* __restrict__ sxk) {
  int bid = blockIdx.x;
  int s = bid >> 7, r = bid & 127;
  int b = r >> 3, h = r & 7;
  int gq = h / 3, gk = (8 + h) / 3;
  const float* A = x + ((size_t)b * 512 + gq * 64) * N_ + s * 1024;
  const float* B = x + ((size_t)b * 512 + gk * 64) * N_ + s * 1024;
  __shared__ __attribute__((aligned(16))) float As[64][68];
  __shared__ __attribute__((aligned(16))) float Bs[64][68];
  int t = threadIdx.x;
  int tx = t & 15, ty = t >> 4;
  int d0 = ty * 4, e0 = tx * 4;
  int lr = t >> 4, lc = (t & 15) * 4;
  float acc[4][4] = {};
  float rsA[4] = {}, rsB[4] = {};
  for (int tile = 0; tile < 16; ++tile) {
    int n0 = tile * 64;
#pragma unroll
    for (int i = 0; i < 4; ++i) {
      int row = lr + 16 * i;
      float4 va = *(const float4*)(A + (size_t)row * N_ + n0 + lc);
      float4 vb = *(const float4*)(B + (size_t)row * N_ + n0 + lc);
      *(float4*)&As[row][lc] = va;
      int sw = ((row >> 2) & 7) << 2;
      *(float4*)&Bs[row][lc ^ sw] = vb;
      rsA[i] += va.x + va.y + va.z + va.w;
      rsB[i] += vb.x + vb.y + vb.z + vb.w;
    }
    __syncthreads();
    int swr = (tx & 7) << 2;
#pragma unroll
    for (int nn = 0; nn < 64; nn += 4) {
      float4 a4[4], b4[4];
#pragma unroll
      for (int i = 0; i < 4; ++i) a4[i] = *(const float4*)&As[d0 + i][nn];
      int cb = nn ^ swr;
#pragma unroll
      for (int j = 0; j < 4; ++j) b4[j] = *(const float4*)&Bs[e0 + j][cb];
#pragma unroll
      for (int i = 0; i < 4; ++i)
#pragma unroll
        for (int j = 0; j < 4; ++j)
          acc[i][j] += a4[i].x * b4[j].x + a4[i].y * b4[j].y
                     + a4[i].z * b4[j].z + a4[i].w * b4[j].w;
    }
    __syncthreads();
  }
  size_t base = ((size_t)s * 128 + r) * 4096;
#pragma unroll
  for (int i = 0; i < 4; ++i)
#pragma unroll
    for (int j = 0; j < 4; ++j)
      Gp[base + (size_t)(d0 + i) * 64 + e0 + j] = acc[i][j];
  // reduce row sums across the 16 threads per row group
#pragma unroll
  for (int i = 0; i < 4; ++i)
#pragma unroll
    for (int m = 1; m < 16; m <<= 1) {
      rsA[i] += __shfl_xor(rsA[i], m);
      rsB[i] += __shfl_xor(rsB[i], m);
    }
  if (tx == 0) {
    size_t sb = ((size_t)s * 128 + r) * 64;
#pragma unroll
    for (int i = 0; i < 4; ++i) {
      sxq[sb + lr + 16 * i] = rsA[i];
      sxk[sb + lr + 16 * i] = rsB[i];
    }
  }
}

// ---------------- K2: per-(b,h) attention algebra ----------------
__global__ __launch_bounds__(256) void k2_attn1(
    const float* __restrict__ w1, const float* __restrict__ b1,
    const float* __restrict__ Gp, const float* __restrict__ sxqp,
    const float* __restrict__ sxkp,
    float* __restrict__ M1, float* __restrict__ pbv1) {
  int bh = blockIdx.x;
  int h = bh & 7;
  int mq = h, mk = 8 + h, mv = 16 + h;
  int gq = mq / 3, oq0 = (mq % 3) * 64;
  int gk = mk / 3, ok0 = (mk % 3) * 64;
  int gv = mv / 3, ov0 = (mv % 3) * 64;
  __shared__ __attribute__((aligned(16))) float Gs[64][68];   // G, later P
  __shared__ __attribute__((aligned(16))) float Was[64][68];  // Wq, later Wv
  __shared__ __attribute__((aligned(16))) float Wbs[64][68];  // Wk
  __shared__ __attribute__((aligned(16))) float Ts[64][68];   // tq = Wq@G
  __shared__ float sxs[64], sks[64], vqs[64], vks[64], bvs[64];
  int t = threadIdx.x, tx = t & 15, ty = t >> 4;
  int d0 = ty * 4, e0 = tx * 4;

  for (int f = t; f < 4096; f += 256) {
    int dd = f >> 6, ee = f & 63;
    float g = 0.f;
#pragma unroll
    for (int s = 0; s < 4; ++s) g += Gp[(((size_t)s * 128 + bh) * 64 + dd) * 64 + ee];
    Gs[dd][ee] = g;
    Was[dd][ee] = w1[((size_t)(gq * 192 + oq0 + dd)) * 64 + ee];
    Wbs[dd][ee] = w1[((size_t)(gk * 192 + ok0 + dd)) * 64 + ee];
  }
  if (t < 64) {
    float v = 0.f, w = 0.f;
#pragma unroll
    for (int s = 0; s < 4; ++s) {
      v += sxqp[((size_t)s * 128 + bh) * 64 + t];
      w += sxkp[((size_t)s * 128 + bh) * 64 + t];
    }
    sxs[t] = v; sks[t] = w;
    bvs[t] = b1[gv * 192 + ov0 + t];
  }
  __syncthreads();
  if (t < 64) {
    float vq = 0.f, vk = 0.f;
    for (int i = 0; i < 64; ++i) { vq += Was[t][i] * sxs[i]; vk += Wbs[t][i] * sks[i]; }
    vqs[t] = vq; vks[t] = vk;
  }
  // tq = Wq @ G
  {
    float acc[4][4] = {};
    for (int i = 0; i < 64; i += 4) {
      float4 a4[4], g4[4];
#pragma unroll
      for (int r = 0; r < 4; ++r) a4[r] = *(const float4*)&Was[d0 + r][i];
#pragma unroll
      for (int k = 0; k < 4; ++k) g4[k] = *(const float4*)&Gs[i + k][e0];
#pragma unroll
      for (int r = 0; r < 4; ++r) {
        const float* ap = (const float*)&a4[r];
#pragma unroll
        for (int k = 0; k < 4; ++k) {
          const float* gp = (const float*)&g4[k];
#pragma unroll
          for (int c = 0; c < 4; ++c) acc[r][c] += ap[k] * gp[c];
        }
      }
    }
#pragma unroll
    for (int r = 0; r < 4; ++r)
#pragma unroll
      for (int c = 0; c < 4; ++c) Ts[d0 + r][e0 + c] = acc[r][c];
  }
  __syncthreads();
  // S = Ts @ Wk^T + bias terms; scale; signed-sqrt; row softmax
  float P[4][4];
  {
    float s[4][4] = {};
    for (int j = 0; j < 64; j += 4) {
      float4 t4[4], w4[4];
#pragma unroll
      for (int r = 0; r < 4; ++r) t4[r] = *(const float4*)&Ts[d0 + r][j];
#pragma unroll
      for (int c = 0; c < 4; ++c) w4[c] = *(const float4*)&Wbs[e0 + c][j];
#pragma unroll
      for (int r = 0; r < 4; ++r)
#pragma unroll
        for (int c = 0; c < 4; ++c)
          s[r][c] += t4[r].x * w4[c].x + t4[r].y * w4[c].y
                   + t4[r].z * w4[c].z + t4[r].w * w4[c].w;
    }
    float bq_[4], bk_[4];
#pragma unroll
    for (int r = 0; r < 4; ++r) bq_[r] = b1[gq * 192 + oq0 + d0 + r];
#pragma unroll
    for (int c = 0; c < 4; ++c) bk_[c] = b1[gk * 192 + ok0 + e0 + c];
#pragma unroll
    for (int r = 0; r < 4; ++r)
#pragma unroll
      for (int c = 0; c < 4; ++c) {
        float v = (s[r][c] + bq_[r] * vks[e0 + c] + bk_[c] * vqs[d0 + r]
                   + 4096.f * bq_[r] * bk_[c]) * 0.125f;
        s[r][c] = ssqrt(v);
      }
#pragma unroll
    for (int r = 0; r < 4; ++r) {
      float m = fmaxf(fmaxf(s[r][0], s[r][1]), fmaxf(s[r][2], s[r][3]));
#pragma unroll
      for (int mm = 1; mm < 16; mm <<= 1) m = fmaxf(m, __shfl_xor(m, mm));
      float sum = 0.f;
#pragma unroll
      for (int c = 0; c < 4; ++c) { s[r][c] = expf(s[r][c] - m); sum += s[r][c]; }
#pragma unroll
      for (int mm = 1; mm < 16; mm <<= 1) sum += __shfl_xor(sum, mm);
      float inv = 1.f / sum;
#pragma unroll
      for (int c = 0; c < 4; ++c) P[r][c] = s[r][c] * inv;
    }
  }
  // store P (reuse Gs), load Wv (reuse Was)
#pragma unroll
  for (int r = 0; r < 4; ++r)
#pragma unroll
    for (int c = 0; c < 4; ++c) Gs[d0 + r][e0 + c] = P[r][c];
  for (int f = t; f < 4096; f += 256) {
    int ee = f >> 6, ii = f & 63;
    Was[ee][ii] = w1[((size_t)(gv * 192 + ov0 + ee)) * 64 + ii];
  }
  __syncthreads();
  // M = P @ Wv
  {
    float acc[4][4] = {};
    for (int e = 0; e < 64; e += 4) {
      float4 p4[4], v4[4];
#pragma unroll
      for (int r = 0; r < 4; ++r) p4[r] = *(const float4*)&Gs[d0 + r][e];
#pragma unroll
      for (int k = 0; k < 4; ++k) v4[k] = *(const float4*)&Was[e + k][e0];
#pragma unroll
      for (int r = 0; r < 4; ++r) {
        const float* pp = (const float*)&p4[r];
#pragma unroll
        for (int k = 0; k < 4; ++k) {
          const float* vp = (const float*)&v4[k];
#pragma unroll
          for (int c = 0; c < 4; ++c) acc[r][c] += pp[k] * vp[c];
        }
      }
    }
    float* Mo = M1 + (size_t)bh * 4096;
#pragma unroll
    for (int r = 0; r < 4; ++r)
#pragma unroll
      for (int c = 0; c < 4; ++c) Mo[(size_t)(d0 + r) * 64 + e0 + c] = acc[r][c];
  }
  if (t < 64) {
    float pb = 0.f;
    for (int e = 0; e < 64; ++e) pb += Gs[t][e] * bvs[e];
    pbv1[(size_t)bh * 64 + t] = pb;
  }
}

// ---------------- K3: out1 = M@Xv + pbv + residual, permute, BN -> y ----------------
__global__ __launch_bounds__(256) void k3_out1(const float* __restrict__ x,
    const float* __restrict__ M1, const float* __restrict__ pbv1,
    const float* __restrict__ gamma, const float* __restrict__ beta,
    const float* __restrict__ rmean, const float* __restrict__ rvar,
    float* __restrict__ y) {
  int bid = blockIdx.x;
  int chunk = bid & 3, bh = bid >> 2;
  int b = bh >> 3, h = bh & 7;
  int gv = (16 + h) / 3;
  const float* Xv = x + ((size_t)b * 512 + gv * 64) * N_ + chunk * 1024;
  const float* Xr = x + ((size_t)b * 512 + h * 64) * N_ + chunk * 1024;
  const float* M = M1 + (size_t)bh * 4096;
  float* Y = y + (size_t)b * 512 * N_ + chunk * 1024;
  __shared__ __attribute__((aligned(16))) float Ms[64][68];
  __shared__ __attribute__((aligned(16))) float Xs[64][68];
  __shared__ float pbs[64], invs[64], adds[64];
  int t = threadIdx.x, tx = t & 15, ty = t >> 4;
  int d0 = ty * 4, j0 = tx * 4;
  for (int f = t; f < 4096; f += 256) Ms[f >> 6][f & 63] = M[f];
  if (t < 64) {
    pbs[t] = pbv1[(size_t)bh * 64 + t];
    int c = t * 8 + h;
    float iv = gamma[c] / sqrtf(rvar[c] + 1e-5f);
    invs[t] = iv;
    adds[t] = beta[c] - rmean[c] * iv;
  }
  __syncthreads();
  int lr = t >> 4, lc = (t & 15) * 4;
  for (int tile = 0; tile < 16; ++tile) {
    int n0 = tile * 64;
#pragma unroll
    for (int i = 0; i < 4; ++i) {
      int row = lr + 16 * i;
      *(float4*)&Xs[row][lc] = *(const float4*)(Xv + (size_t)row * N_ + n0 + lc);
    }
    __syncthreads();
    float acc[4][4] = {};
    for (int e = 0; e < 64; e += 4) {
      float4 a4[4], x4[4];
#pragma unroll
      for (int r = 0; r < 4; ++r) a4[r] = *(const float4*)&Ms[d0 + r][e];
#pragma unroll
      for (int k = 0; k < 4; ++k) x4[k] = *(const float4*)&Xs[e + k][j0];
#pragma unroll
      for (int r = 0; r < 4; ++r) {
        const float* ap = (const float*)&a4[r];
#pragma unroll
        for (int k = 0; k < 4; ++k) {
          const float* xp = (const float*)&x4[k];
#pragma unroll
          for (int c = 0; c < 4; ++c) acc[r][c] += ap[k] * xp[c];
        }
      }
    }
#pragma unroll
    for (int r = 0; r < 4; ++r) {
      int d = d0 + r;
      float4 rx = *(const float4*)(Xr + (size_t)d * N_ + n0 + j0);
      float4 v;
      v.x = (acc[r][0] + pbs[d] + rx.x) * invs[d] + adds[d];
      v.y = (acc[r][1] + pbs[d] + rx.y) * invs[d] + adds[d];
      v.z = (acc[r][2] + pbs[d] + rx.z) * invs[d] + adds[d];
      v.w = (acc[r][3] + pbs[d] + rx.w) * invs[d] + adds[d];
      *(float4*)(Y + (size_t)(d * 8 + h) * N_ + n0 + j0) = v;
    }
    __syncthreads();
  }
}

// ---------------- K4: Gram for stage 2 over relu(y) ----------------
__global__ __launch_bounds__(256) void k4_gram2(const float* __restrict__ y,
    float* __restrict__ G2, float* __restrict__ sq2, float* __restrict__ sk2) {
  int bid = blockIdx.x;
  int b = bid >> 6, d = bid & 63;
  int gq = d / 3, gk = (64 + d) / 3;
  const float* Aq = y + ((size_t)b * 512 + gq * 8) * N_;
  const float* Ak = y + ((size_t)b * 512 + gk * 8) * N_;
  int t = threadIdx.x;
  float acc[8][8] = {};
  float sq[8] = {}, sk[8] = {};
  for (int n = t; n < N_; n += 256) {
    float a[8], c[8];
#pragma unroll
    for (int i = 0; i < 8; ++i) { a[i] = fmaxf(Aq[(size_t)i * N_ + n], 0.f); sq[i] += a[i]; }
#pragma unroll
    for (int j = 0; j < 8; ++j) { c[j] = fmaxf(Ak[(size_t)j * N_ + n], 0.f); sk[j] += c[j]; }
#pragma unroll
    for (int i = 0; i < 8; ++i)
#pragma unroll
      for (int j = 0; j < 8; ++j) acc[i][j] += a[i] * c[j];
  }
#pragma unroll
  for (int i = 0; i < 8; ++i)
#pragma unroll
    for (int j = 0; j < 8; ++j)
#pragma unroll
      for (int m = 1; m < 64; m <<= 1) acc[i][j] += __shfl_xor(acc[i][j], m);
#pragma unroll
  for (int i = 0; i < 8; ++i)
#pragma unroll
    for (int m = 1; m < 64; m <<= 1) {
      sq[i] += __shfl_xor(sq[i], m);
      sk[i] += __shfl_xor(sk[i], m);
    }
  __shared__ float red[4][96];
  int wave = t >> 6, lane = t & 63;
  if (lane == 0) {
#pragma unroll
    for (int i = 0; i < 8; ++i) {
#pragma unroll
      for (int j = 0; j < 8; ++j) red[wave][i * 8 + j] = acc[i][j];
      red[wave][64 + i] = sq[i];
      red[wave][72 + i] = sk[i];
    }
  }
  __syncthreads();
  if (t < 80) {
    float v = red[0][t] + red[1][t] + red[2][t] + red[3][t];
    size_t bd = (size_t)bid;
    if (t < 64) G2[bd * 64 + t] = v;
    else if (t < 72) sq2[bd * 8 + (t - 64)] = v;
    else sk2[bd * 8 + (t - 72)] = v;
  }
}

// ---------------- K5: per-(b,d) stage-2 attention algebra ----------------
__global__ __launch_bounds__(64) void k5_attn2(
    const float* __restrict__ w2, const float* __restrict__ b2,
    const float* __restrict__ G2, const float* __restrict__ sq2,
    const float* __restrict__ sk2,
    float* __restrict__ M2, float* __restrict__ pbv2) {
  int bid = blockIdx.x;
  int d = bid & 63;
  int mq = d, mk = 64 + d, mv = 128 + d;
  int gq = mq / 3, oq0 = (mq % 3) * 8;
  int gk = mk / 3, ok0 = (mk % 3) * 8;
  int gv = mv / 3, ov0 = (mv % 3) * 8;
  __shared__ float Gs[8][8], Wq[8][8], Wk[8][8], Wv[8][8];
  __shared__ float bq[8], bk[8], bv[8], sq[8], sk[8], Ps[8][9];
  int t = threadIdx.x;
  int hh = t >> 3, ee = t & 7;
  Gs[hh][ee] = G2[(size_t)bid * 64 + t];
  Wq[hh][ee] = w2[(size_t)(gq * 24 + oq0 + hh) * 8 + ee];
  Wk[hh][ee] = w2[(size_t)(gk * 24 + ok0 + hh) * 8 + ee];
  Wv[hh][ee] = w2[(size_t)(gv * 24 + ov0 + hh) * 8 + ee];
  if (t < 8) {
    bq[t] = b2[gq * 24 + oq0 + t];
    bk[t] = b2[gk * 24 + ok0 + t];
    bv[t] = b2[gv * 24 + ov0 + t];
    sq[t] = sq2[(size_t)bid * 8 + t];
    sk[t] = sk2[(size_t)bid * 8 + t];
  }
  __syncthreads();
  float s = 0.f;
#pragma unroll
  for (int i = 0; i < 8; ++i) {
    float pg = 0.f;
#pragma unroll
    for (int j = 0; j < 8; ++j) pg += Gs[i][j] * Wk[ee][j];
    s += Wq[hh][i] * pg;
  }
  float dq = 0.f, dk = 0.f;
#pragma unroll
  for (int i = 0; i < 8; ++i) { dq += Wq[hh][i] * sq[i]; dk += Wk[ee][i] * sk[i]; }
  s = (s + bq[hh] * dk + bk[ee] * dq + 4096.f * bq[hh] * bk[ee]) * 0.35355339059327373f;
  s = ssqrt(s);
  float m = s;
#pragma unroll
  for (int mm = 1; mm < 8; mm <<= 1) m = fmaxf(m, __shfl_xor(m, mm));
  float p = expf(s - m);
  float sum = p;
#pragma unroll
  for (int mm = 1; mm < 8; mm <<= 1) sum += __shfl_xor(sum, mm);
  p /= sum;
  Ps[hh][ee] = p;
  __syncthreads();
  float mo = 0.f;
#pragma unroll
  for (int e = 0; e < 8; ++e) mo += Ps[hh][e] * Wv[e][ee];
  M2[(size_t)bid * 64 + t] = mo;
  if (t < 8) {
    float pb = 0.f;
#pragma unroll
    for (int e = 0; e < 8; ++e) pb += Ps[t][e] * bv[e];
    pbv2[(size_t)bid * 8 + t] = pb;
  }
}

// ---------------- K6: x2 = M2@relu(y_v) + pbv2 + y(residual) -> out ----------------
__global__ __launch_bounds__(256) void k6_final(const float* __restrict__ y,
    const float* __restrict__ M2, const float* __restrict__ pbv2,
    float* __restrict__ out) {
  int bid = blockIdx.x;
  int b = bid >> 6, d = bid & 63;
  int gv = (128 + d) / 3;
  const float* Yv = y + ((size_t)b * 512 + gv * 8) * N_;
  // residual: x2[b, hh*64+d, n] += y[b, hh*64+d, n]  (post-permute channel!)
  const float* Yr = y + ((size_t)b * 512 + d) * N_;
  float* O = out + ((size_t)b * 512 + d) * N_;
  __shared__ float Ms[8][8];
  __shared__ float pbs[8];
  int t = threadIdx.x;
  if (t < 64) Ms[t >> 3][t & 7] = M2[(size_t)bid * 64 + t];
  if (t < 8) pbs[t] = pbv2[(size_t)bid * 8 + t];
  __syncthreads();
  for (int n4 = t; n4 < 1024; n4 += 256) {
    float4 xv[8];
#pragma unroll
    for (int i = 0; i < 8; ++i) {
      float4 v = *(const float4*)(Yv + (size_t)i * N_ + n4 * 4);
      v.x = fmaxf(v.x, 0.f); v.y = fmaxf(v.y, 0.f);
      v.z = fmaxf(v.z, 0.f); v.w = fmaxf(v.w, 0.f);
      xv[i] = v;
    }
#pragma unroll
    for (int hh = 0; hh < 8; ++hh) {
      float pb = pbs[hh];
      float4 acc; acc.x = pb; acc.y = pb; acc.z = pb; acc.w = pb;
#pragma unroll
      for (int i = 0; i < 8; ++i) {
        float mw = Ms[hh][i];
        acc.x += mw * xv[i].x; acc.y += mw * xv[i].y;
        acc.z += mw * xv[i].z; acc.w += mw * xv[i].w;
      }
      float4 yr = *(const float4*)(Yr + (size_t)hh * 64 * N_ + n4 * 4);
      acc.x += yr.x; acc.y += yr.y; acc.z += yr.z; acc.w += yr.w;
      *(float4*)(O + (size_t)hh * 64 * N_ + n4 * 4) = acc;
    }
  }
}

extern "C" void kernel_launch(void* const* d_in, const int* in_sizes, int n_in,
                              void* d_out, int out_size, void* d_ws, size_t ws_size,
                              hipStream_t stream) {
  const float* x     = (const float*)d_in[0];
  const float* w1    = (const float*)d_in[1];
  const float* b1    = (const float*)d_in[2];
  const float* w2    = (const float*)d_in[3];
  const float* b2    = (const float*)d_in[4];
  const float* gamma = (const float*)d_in[5];
  const float* beta  = (const float*)d_in[6];
  const float* rmean = (const float*)d_in[7];
  const float* rvar  = (const float*)d_in[8];
  float* out = (float*)d_out;
  float* ws = (float*)d_ws;

  // workspace layout (floats)
  float* y    = ws;                 // 33,554,432
  float* Gp   = y + 33554432;       //  2,097,152
  float* sxq  = Gp + 2097152;       //     32,768
  float* sxk  = sxq + 32768;        //     32,768
  float* M1   = sxk + 32768;        //    524,288
  float* pbv1 = M1 + 524288;        //      8,192
  float* G2   = pbv1 + 8192;        //     65,536
  float* sq2  = G2 + 65536;         //      8,192
  float* sk2  = sq2 + 8192;         //      8,192
  float* M2   = sk2 + 8192;         //     65,536
  float* pbv2 = M2 + 65536;         //      8,192
  size_t need = (size_t)36405248 * sizeof(float);
  if (ws_size < need) return;  // fail validation cleanly rather than corrupt

  k1_gram<<<512, 256, 0, stream>>>(x, Gp, sxq, sxk);
  k2_attn1<<<128, 256, 0, stream>>>(w1, b1, Gp, sxq, sxk, M1, pbv1);
  k3_out1<<<512, 256, 0, stream>>>(x, M1, pbv1, gamma, beta, rmean, rvar, y);
  k4_gram2<<<1024, 256, 0, stream>>>(y, G2, sq2, sk2);
  k5_attn2<<<1024, 64, 0, stream>>>(w2, b2, G2, sq2, sk2, M2, pbv2);
  k6_final<<<1024, 256, 0, stream>>>(y, M2, pbv2, out);
}

// Round 3
// 274.789 us; speedup vs baseline: 1.3923x; 1.3923x over previous
//
#include <hip/hip_runtime.h>

#define N_ 4096

typedef __attribute__((ext_vector_type(8))) short bf16x8;
typedef __attribute__((ext_vector_type(4))) float f32x4;

__device__ __forceinline__ float ssqrt(float a) {
  if (a == 0.f) return 0.f;
  return copysignf(sqrtf(fabsf(a) + 1e-5f), a);
}

__device__ __forceinline__ ushort f2bf(float f) {
  uint u = __float_as_uint(f);
  u += 0x7fff + ((u >> 16) & 1);  // RNE
  return (ushort)(u >> 16);
}
__device__ __forceinline__ float bf2f(ushort h) {
  return __uint_as_float((uint)h << 16);
}

__device__ __forceinline__ f32x4 mfma16(bf16x8 a, bf16x8 b, f32x4 c) {
  return __builtin_amdgcn_mfma_f32_16x16x32_bf16(a, b, c, 0, 0, 0);
}

// ---------------- K1: Gram for stage 1 (MFMA bf16x3) ----------------
// G[s][b][h][d][e] = sum_{n in split s} Xq[d,n]*Xk[e,n]; also row sums.
__global__ __launch_bounds__(256) void k1_gram(const float* __restrict__ x,
    float* __restrict__ Gp, float* __restrict__ sxq, float* __restrict__ sxk) {
  int bid = blockIdx.x;
  int s = bid >> 7, r = bid & 127;
  int b = r >> 3, h = r & 7;
  int gq = h / 3, gk = (8 + h) / 3;
  const float* A = x + ((size_t)b * 512 + gq * 64) * N_ + s * 1024;
  const float* B = x + ((size_t)b * 512 + gk * 64) * N_ + s * 1024;
  // 72-short row stride (144 B) -> 2-way bank aliasing only (free)
  __shared__ __attribute__((aligned(16))) ushort Ah[64][72], Al[64][72];
  __shared__ __attribute__((aligned(16))) ushort Bh[64][72], Bl[64][72];
  int t = threadIdx.x;
  int lr = t >> 2, lq = t & 3;           // staging: row, 16-float k-chunk
  int l = t & 63, w = t >> 6;
  int mw = (w >> 1) * 32, nw = (w & 1) * 32;  // wave's 32x32 quadrant
  int fr = l & 15, ko = (l >> 4) * 8;
  float sumA = 0.f, sumB = 0.f;
  f32x4 acc[2][2];
#pragma unroll
  for (int i = 0; i < 2; ++i)
#pragma unroll
    for (int j = 0; j < 2; ++j) acc[i][j] = (f32x4){0.f, 0.f, 0.f, 0.f};

  for (int kt = 0; kt < 16; ++kt) {
    int kbase = kt * 64 + lq * 16;
#pragma unroll
    for (int j = 0; j < 4; ++j) {
      float4 va = *(const float4*)(A + (size_t)lr * N_ + kbase + j * 4);
      float4 vb = *(const float4*)(B + (size_t)lr * N_ + kbase + j * 4);
      sumA += va.x + va.y + va.z + va.w;
      sumB += vb.x + vb.y + vb.z + vb.w;
      ushort4 ha, la, hb, lb;
      ha.x = f2bf(va.x); ha.y = f2bf(va.y); ha.z = f2bf(va.z); ha.w = f2bf(va.w);
      la.x = f2bf(va.x - bf2f(ha.x)); la.y = f2bf(va.y - bf2f(ha.y));
      la.z = f2bf(va.z - bf2f(ha.z)); la.w = f2bf(va.w - bf2f(ha.w));
      hb.x = f2bf(vb.x); hb.y = f2bf(vb.y); hb.z = f2bf(vb.z); hb.w = f2bf(vb.w);
      lb.x = f2bf(vb.x - bf2f(hb.x)); lb.y = f2bf(vb.y - bf2f(hb.y));
      lb.z = f2bf(vb.z - bf2f(hb.z)); lb.w = f2bf(vb.w - bf2f(hb.w));
      int c0 = lq * 16 + j * 4;
      *(ushort4*)&Ah[lr][c0] = ha;
      *(ushort4*)&Al[lr][c0] = la;
      *(ushort4*)&Bh[lr][c0] = hb;
      *(ushort4*)&Bl[lr][c0] = lb;
    }
    __syncthreads();
#pragma unroll
    for (int wk = 0; wk < 2; ++wk) {
      int kk = wk * 32 + ko;
      bf16x8 ah[2], al[2], bh[2], bl[2];
#pragma unroll
      for (int mt = 0; mt < 2; ++mt) {
        ah[mt] = *(const bf16x8*)&Ah[mw + mt * 16 + fr][kk];
        al[mt] = *(const bf16x8*)&Al[mw + mt * 16 + fr][kk];
      }
#pragma unroll
      for (int nt = 0; nt < 2; ++nt) {
        bh[nt] = *(const bf16x8*)&Bh[nw + nt * 16 + fr][kk];
        bl[nt] = *(const bf16x8*)&Bl[nw + nt * 16 + fr][kk];
      }
#pragma unroll
      for (int mt = 0; mt < 2; ++mt)
#pragma unroll
        for (int nt = 0; nt < 2; ++nt) {
          acc[mt][nt] = mfma16(ah[mt], bh[nt], acc[mt][nt]);
          acc[mt][nt] = mfma16(ah[mt], bl[nt], acc[mt][nt]);
          acc[mt][nt] = mfma16(al[mt], bh[nt], acc[mt][nt]);
        }
    }
    __syncthreads();
  }
  size_t base = ((size_t)s * 128 + r) * 4096;
#pragma unroll
  for (int mt = 0; mt < 2; ++mt)
#pragma unroll
    for (int nt = 0; nt < 2; ++nt)
#pragma unroll
      for (int reg = 0; reg < 4; ++reg) {
        int gr = mw + mt * 16 + (l >> 4) * 4 + reg;
        int gc = nw + nt * 16 + fr;
        Gp[base + (size_t)gr * 64 + gc] = acc[mt][nt][reg];
      }
  // row sums: lanes lr*4+lq share row lr
  sumA += __shfl_xor(sumA, 1); sumA += __shfl_xor(sumA, 2);
  sumB += __shfl_xor(sumB, 1); sumB += __shfl_xor(sumB, 2);
  if (lq == 0) {
    size_t sb = ((size_t)s * 128 + r) * 64;
    sxq[sb + lr] = sumA;
    sxk[sb + lr] = sumB;
  }
}

// ---------------- K2: per-(b,h) attention algebra ----------------
__global__ __launch_bounds__(256) void k2_attn1(
    const float* __restrict__ w1, const float* __restrict__ b1,
    const float* __restrict__ Gp, const float* __restrict__ sxqp,
    const float* __restrict__ sxkp,
    float* __restrict__ M1, float* __restrict__ pbv1) {
  int bh = blockIdx.x;
  int h = bh & 7;
  int mq = h, mk = 8 + h, mv = 16 + h;
  int gq = mq / 3, oq0 = (mq % 3) * 64;
  int gk = mk / 3, ok0 = (mk % 3) * 64;
  int gv = mv / 3, ov0 = (mv % 3) * 64;
  __shared__ __attribute__((aligned(16))) float Gs[64][68];   // G, later P
  __shared__ __attribute__((aligned(16))) float Was[64][68];  // Wq, later Wv
  __shared__ __attribute__((aligned(16))) float Wbs[64][68];  // Wk
  __shared__ __attribute__((aligned(16))) float Ts[64][68];   // tq = Wq@G
  __shared__ float sxs[64], sks[64], vqs[64], vks[64], bvs[64];
  int t = threadIdx.x, tx = t & 15, ty = t >> 4;
  int d0 = ty * 4, e0 = tx * 4;

  for (int f = t; f < 4096; f += 256) {
    int dd = f >> 6, ee = f & 63;
    float g = 0.f;
#pragma unroll
    for (int s = 0; s < 4; ++s) g += Gp[(((size_t)s * 128 + bh) * 64 + dd) * 64 + ee];
    Gs[dd][ee] = g;
    Was[dd][ee] = w1[((size_t)(gq * 192 + oq0 + dd)) * 64 + ee];
    Wbs[dd][ee] = w1[((size_t)(gk * 192 + ok0 + dd)) * 64 + ee];
  }
  if (t < 64) {
    float v = 0.f, w = 0.f;
#pragma unroll
    for (int s = 0; s < 4; ++s) {
      v += sxqp[((size_t)s * 128 + bh) * 64 + t];
      w += sxkp[((size_t)s * 128 + bh) * 64 + t];
    }
    sxs[t] = v; sks[t] = w;
    bvs[t] = b1[gv * 192 + ov0 + t];
  }
  __syncthreads();
  if (t < 64) {
    float vq = 0.f, vk = 0.f;
    for (int i = 0; i < 64; ++i) { vq += Was[t][i] * sxs[i]; vk += Wbs[t][i] * sks[i]; }
    vqs[t] = vq; vks[t] = vk;
  }
  // tq = Wq @ G
  {
    float acc[4][4] = {};
    for (int i = 0; i < 64; i += 4) {
      float4 a4[4], g4[4];
#pragma unroll
      for (int r = 0; r < 4; ++r) a4[r] = *(const float4*)&Was[d0 + r][i];
#pragma unroll
      for (int k = 0; k < 4; ++k) g4[k] = *(const float4*)&Gs[i + k][e0];
#pragma unroll
      for (int r = 0; r < 4; ++r) {
        const float* ap = (const float*)&a4[r];
#pragma unroll
        for (int k = 0; k < 4; ++k) {
          const float* gp = (const float*)&g4[k];
#pragma unroll
          for (int c = 0; c < 4; ++c) acc[r][c] += ap[k] * gp[c];
        }
      }
    }
#pragma unroll
    for (int r = 0; r < 4; ++r)
#pragma unroll
      for (int c = 0; c < 4; ++c) Ts[d0 + r][e0 + c] = acc[r][c];
  }
  __syncthreads();
  // S = Ts @ Wk^T + bias terms; scale; signed-sqrt; row softmax
  float P[4][4];
  {
    float s[4][4] = {};
    for (int j = 0; j < 64; j += 4) {
      float4 t4[4], w4[4];
#pragma unroll
      for (int r = 0; r < 4; ++r) t4[r] = *(const float4*)&Ts[d0 + r][j];
#pragma unroll
      for (int c = 0; c < 4; ++c) w4[c] = *(const float4*)&Wbs[e0 + c][j];
#pragma unroll
      for (int r = 0; r < 4; ++r)
#pragma unroll
        for (int c = 0; c < 4; ++c)
          s[r][c] += t4[r].x * w4[c].x + t4[r].y * w4[c].y
                   + t4[r].z * w4[c].z + t4[r].w * w4[c].w;
    }
    float bq_[4], bk_[4];
#pragma unroll
    for (int r = 0; r < 4; ++r) bq_[r] = b1[gq * 192 + oq0 + d0 + r];
#pragma unroll
    for (int c = 0; c < 4; ++c) bk_[c] = b1[gk * 192 + ok0 + e0 + c];
#pragma unroll
    for (int r = 0; r < 4; ++r)
#pragma unroll
      for (int c = 0; c < 4; ++c) {
        float v = (s[r][c] + bq_[r] * vks[e0 + c] + bk_[c] * vqs[d0 + r]
                   + 4096.f * bq_[r] * bk_[c]) * 0.125f;
        s[r][c] = ssqrt(v);
      }
#pragma unroll
    for (int r = 0; r < 4; ++r) {
      float m = fmaxf(fmaxf(s[r][0], s[r][1]), fmaxf(s[r][2], s[r][3]));
#pragma unroll
      for (int mm = 1; mm < 16; mm <<= 1) m = fmaxf(m, __shfl_xor(m, mm));
      float sum = 0.f;
#pragma unroll
      for (int c = 0; c < 4; ++c) { s[r][c] = expf(s[r][c] - m); sum += s[r][c]; }
#pragma unroll
      for (int mm = 1; mm < 16; mm <<= 1) sum += __shfl_xor(sum, mm);
      float inv = 1.f / sum;
#pragma unroll
      for (int c = 0; c < 4; ++c) P[r][c] = s[r][c] * inv;
    }
  }
  // store P (reuse Gs), load Wv (reuse Was)
#pragma unroll
  for (int r = 0; r < 4; ++r)
#pragma unroll
    for (int c = 0; c < 4; ++c) Gs[d0 + r][e0 + c] = P[r][c];
  for (int f = t; f < 4096; f += 256) {
    int ee = f >> 6, ii = f & 63;
    Was[ee][ii] = w1[((size_t)(gv * 192 + ov0 + ee)) * 64 + ii];
  }
  __syncthreads();
  // M = P @ Wv
  {
    float acc[4][4] = {};
    for (int e = 0; e < 64; e += 4) {
      float4 p4[4], v4[4];
#pragma unroll
      for (int r = 0; r < 4; ++r) p4[r] = *(const float4*)&Gs[d0 + r][e];
#pragma unroll
      for (int k = 0; k < 4; ++k) v4[k] = *(const float4*)&Was[e + k][e0];
#pragma unroll
      for (int r = 0; r < 4; ++r) {
        const float* pp = (const float*)&p4[r];
#pragma unroll
        for (int k = 0; k < 4; ++k) {
          const float* vp = (const float*)&v4[k];
#pragma unroll
          for (int c = 0; c < 4; ++c) acc[r][c] += pp[k] * vp[c];
        }
      }
    }
    float* Mo = M1 + (size_t)bh * 4096;
#pragma unroll
    for (int r = 0; r < 4; ++r)
#pragma unroll
      for (int c = 0; c < 4; ++c) Mo[(size_t)(d0 + r) * 64 + e0 + c] = acc[r][c];
  }
  if (t < 64) {
    float pb = 0.f;
    for (int e = 0; e < 64; ++e) pb += Gs[t][e] * bvs[e];
    pbv1[(size_t)bh * 64 + t] = pb;
  }
}

// ---------------- K3: out1 = M@Xv + pbv + residual, permute, BN -> y ----------------
__global__ __launch_bounds__(256) void k3_out1(const float* __restrict__ x,
    const float* __restrict__ M1, const float* __restrict__ pbv1,
    const float* __restrict__ gamma, const float* __restrict__ beta,
    const float* __restrict__ rmean, const float* __restrict__ rvar,
    float* __restrict__ y) {
  int bid = blockIdx.x;
  int chunk = bid & 3, bh = bid >> 2;
  int b = bh >> 3, h = bh & 7;
  int gv = (16 + h) / 3;
  const float* Xv = x + ((size_t)b * 512 + gv * 64) * N_ + chunk * 1024;
  const float* Xr = x + ((size_t)b * 512 + h * 64) * N_ + chunk * 1024;
  const float* M = M1 + (size_t)bh * 4096;
  float* Y = y + (size_t)b * 512 * N_ + chunk * 1024;
  __shared__ __attribute__((aligned(16))) float Ms[64][68];
  __shared__ __attribute__((aligned(16))) float Xs[64][68];
  __shared__ float pbs[64], invs[64], adds[64];
  int t = threadIdx.x, tx = t & 15, ty = t >> 4;
  int d0 = ty * 4, j0 = tx * 4;
  for (int f = t; f < 4096; f += 256) Ms[f >> 6][f & 63] = M[f];
  if (t < 64) {
    pbs[t] = pbv1[(size_t)bh * 64 + t];
    int c = t * 8 + h;
    float iv = gamma[c] / sqrtf(rvar[c] + 1e-5f);
    invs[t] = iv;
    adds[t] = beta[c] - rmean[c] * iv;
  }
  __syncthreads();
  int lr = t >> 4, lc = (t & 15) * 4;
  for (int tile = 0; tile < 16; ++tile) {
    int n0 = tile * 64;
#pragma unroll
    for (int i = 0; i < 4; ++i) {
      int row = lr + 16 * i;
      *(float4*)&Xs[row][lc] = *(const float4*)(Xv + (size_t)row * N_ + n0 + lc);
    }
    __syncthreads();
    float acc[4][4] = {};
    for (int e = 0; e < 64; e += 4) {
      float4 a4[4], x4[4];
#pragma unroll
      for (int r = 0; r < 4; ++r) a4[r] = *(const float4*)&Ms[d0 + r][e];
#pragma unroll
      for (int k = 0; k < 4; ++k) x4[k] = *(const float4*)&Xs[e + k][j0];
#pragma unroll
      for (int r = 0; r < 4; ++r) {
        const float* ap = (const float*)&a4[r];
#pragma unroll
        for (int k = 0; k < 4; ++k) {
          const float* xp = (const float*)&x4[k];
#pragma unroll
          for (int c = 0; c < 4; ++c) acc[r][c] += ap[k] * xp[c];
        }
      }
    }
#pragma unroll
    for (int r = 0; r < 4; ++r) {
      int d = d0 + r;
      float4 rx = *(const float4*)(Xr + (size_t)d * N_ + n0 + j0);
      float4 v;
      v.x = (acc[r][0] + pbs[d] + rx.x) * invs[d] + adds[d];
      v.y = (acc[r][1] + pbs[d] + rx.y) * invs[d] + adds[d];
      v.z = (acc[r][2] + pbs[d] + rx.z) * invs[d] + adds[d];
      v.w = (acc[r][3] + pbs[d] + rx.w) * invs[d] + adds[d];
      *(float4*)(Y + (size_t)(d * 8 + h) * N_ + n0 + j0) = v;
    }
    __syncthreads();
  }
}

// ---------------- K4: Gram for stage 2 over relu(y) ----------------
__global__ __launch_bounds__(256) void k4_gram2(const float* __restrict__ y,
    float* __restrict__ G2, float* __restrict__ sq2, float* __restrict__ sk2) {
  int bid = blockIdx.x;
  int b = bid >> 6, d = bid & 63;
  int gq = d / 3, gk = (64 + d) / 3;
  const float* Aq = y + ((size_t)b * 512 + gq * 8) * N_;
  const float* Ak = y + ((size_t)b * 512 + gk * 8) * N_;
  int t = threadIdx.x;
  float acc[8][8] = {};
  float sq[8] = {}, sk[8] = {};
  for (int n = t; n < N_; n += 256) {
    float a[8], c[8];
#pragma unroll
    for (int i = 0; i < 8; ++i) { a[i] = fmaxf(Aq[(size_t)i * N_ + n], 0.f); sq[i] += a[i]; }
#pragma unroll
    for (int j = 0; j < 8; ++j) { c[j] = fmaxf(Ak[(size_t)j * N_ + n], 0.f); sk[j] += c[j]; }
#pragma unroll
    for (int i = 0; i < 8; ++i)
#pragma unroll
      for (int j = 0; j < 8; ++j) acc[i][j] += a[i] * c[j];
  }
#pragma unroll
  for (int i = 0; i < 8; ++i)
#pragma unroll
    for (int j = 0; j < 8; ++j)
#pragma unroll
      for (int m = 1; m < 64; m <<= 1) acc[i][j] += __shfl_xor(acc[i][j], m);
#pragma unroll
  for (int i = 0; i < 8; ++i)
#pragma unroll
    for (int m = 1; m < 64; m <<= 1) {
      sq[i] += __shfl_xor(sq[i], m);
      sk[i] += __shfl_xor(sk[i], m);
    }
  __shared__ float red[4][96];
  int wave = t >> 6, lane = t & 63;
  if (lane == 0) {
#pragma unroll
    for (int i = 0; i < 8; ++i) {
#pragma unroll
      for (int j = 0; j < 8; ++j) red[wave][i * 8 + j] = acc[i][j];
      red[wave][64 + i] = sq[i];
      red[wave][72 + i] = sk[i];
    }
  }
  __syncthreads();
  if (t < 80) {
    float v = red[0][t] + red[1][t] + red[2][t] + red[3][t];
    size_t bd = (size_t)bid;
    if (t < 64) G2[bd * 64 + t] = v;
    else if (t < 72) sq2[bd * 8 + (t - 64)] = v;
    else sk2[bd * 8 + (t - 72)] = v;
  }
}

// ---------------- K5: per-(b,d) stage-2 attention algebra ----------------
__global__ __launch_bounds__(64) void k5_attn2(
    const float* __restrict__ w2, const float* __restrict__ b2,
    const float* __restrict__ G2, const float* __restrict__ sq2,
    const float* __restrict__ sk2,
    float* __restrict__ M2, float* __restrict__ pbv2) {
  int bid = blockIdx.x;
  int d = bid & 63;
  int mq = d, mk = 64 + d, mv = 128 + d;
  int gq = mq / 3, oq0 = (mq % 3) * 8;
  int gk = mk / 3, ok0 = (mk % 3) * 8;
  int gv = mv / 3, ov0 = (mv % 3) * 8;
  __shared__ float Gs[8][8], Wq[8][8], Wk[8][8], Wv[8][8];
  __shared__ float bq[8], bk[8], bv[8], sq[8], sk[8], Ps[8][9];
  int t = threadIdx.x;
  int hh = t >> 3, ee = t & 7;
  Gs[hh][ee] = G2[(size_t)bid * 64 + t];
  Wq[hh][ee] = w2[(size_t)(gq * 24 + oq0 + hh) * 8 + ee];
  Wk[hh][ee] = w2[(size_t)(gk * 24 + ok0 + hh) * 8 + ee];
  Wv[hh][ee] = w2[(size_t)(gv * 24 + ov0 + hh) * 8 + ee];
  if (t < 8) {
    bq[t] = b2[gq * 24 + oq0 + t];
    bk[t] = b2[gk * 24 + ok0 + t];
    bv[t] = b2[gv * 24 + ov0 + t];
    sq[t] = sq2[(size_t)bid * 8 + t];
    sk[t] = sk2[(size_t)bid * 8 + t];
  }
  __syncthreads();
  float s = 0.f;
#pragma unroll
  for (int i = 0; i < 8; ++i) {
    float pg = 0.f;
#pragma unroll
    for (int j = 0; j < 8; ++j) pg += Gs[i][j] * Wk[ee][j];
    s += Wq[hh][i] * pg;
  }
  float dq = 0.f, dk = 0.f;
#pragma unroll
  for (int i = 0; i < 8; ++i) { dq += Wq[hh][i] * sq[i]; dk += Wk[ee][i] * sk[i]; }
  s = (s + bq[hh] * dk + bk[ee] * dq + 4096.f * bq[hh] * bk[ee]) * 0.35355339059327373f;
  s = ssqrt(s);
  float m = s;
#pragma unroll
  for (int mm = 1; mm < 8; mm <<= 1) m = fmaxf(m, __shfl_xor(m, mm));
  float p = expf(s - m);
  float sum = p;
#pragma unroll
  for (int mm = 1; mm < 8; mm <<= 1) sum += __shfl_xor(sum, mm);
  p /= sum;
  Ps[hh][ee] = p;
  __syncthreads();
  float mo = 0.f;
#pragma unroll
  for (int e = 0; e < 8; ++e) mo += Ps[hh][e] * Wv[e][ee];
  M2[(size_t)bid * 64 + t] = mo;
  if (t < 8) {
    float pb = 0.f;
#pragma unroll
    for (int e = 0; e < 8; ++e) pb += Ps[t][e] * bv[e];
    pbv2[(size_t)bid * 8 + t] = pb;
  }
}

// ---------------- K6: x2 = M2@relu(y_v) + pbv2 + y(residual) -> out ----------------
__global__ __launch_bounds__(256) void k6_final(const float* __restrict__ y,
    const float* __restrict__ M2, const float* __restrict__ pbv2,
    float* __restrict__ out) {
  int bid = blockIdx.x;
  int b = bid >> 6, d = bid & 63;
  int gv = (128 + d) / 3;
  const float* Yv = y + ((size_t)b * 512 + gv * 8) * N_;
  // residual: x2[b, hh*64+d, n] += y[b, hh*64+d, n]  (post-permute channel!)
  const float* Yr = y + ((size_t)b * 512 + d) * N_;
  float* O = out + ((size_t)b * 512 + d) * N_;
  __shared__ float Ms[8][8];
  __shared__ float pbs[8];
  int t = threadIdx.x;
  if (t < 64) Ms[t >> 3][t & 7] = M2[(size_t)bid * 64 + t];
  if (t < 8) pbs[t] = pbv2[(size_t)bid * 8 + t];
  __syncthreads();
  for (int n4 = t; n4 < 1024; n4 += 256) {
    float4 xv[8];
#pragma unroll
    for (int i = 0; i < 8; ++i) {
      float4 v = *(const float4*)(Yv + (size_t)i * N_ + n4 * 4);
      v.x = fmaxf(v.x, 0.f); v.y = fmaxf(v.y, 0.f);
      v.z = fmaxf(v.z, 0.f); v.w = fmaxf(v.w, 0.f);
      xv[i] = v;
    }
#pragma unroll
    for (int hh = 0; hh < 8; ++hh) {
      float pb = pbs[hh];
      float4 acc; acc.x = pb; acc.y = pb; acc.z = pb; acc.w = pb;
#pragma unroll
      for (int i = 0; i < 8; ++i) {
        float mw = Ms[hh][i];
        acc.x += mw * xv[i].x; acc.y += mw * xv[i].y;
        acc.z += mw * xv[i].z; acc.w += mw * xv[i].w;
      }
      float4 yr = *(const float4*)(Yr + (size_t)hh * 64 * N_ + n4 * 4);
      acc.x += yr.x; acc.y += yr.y; acc.z += yr.z; acc.w += yr.w;
      *(float4*)(O + (size_t)hh * 64 * N_ + n4 * 4) = acc;
    }
  }
}

extern "C" void kernel_launch(void* const* d_in, const int* in_sizes, int n_in,
                              void* d_out, int out_size, void* d_ws, size_t ws_size,
                              hipStream_t stream) {
  const float* x     = (const float*)d_in[0];
  const float* w1    = (const float*)d_in[1];
  const float* b1    = (const float*)d_in[2];
  const float* w2    = (const float*)d_in[3];
  const float* b2    = (const float*)d_in[4];
  const float* gamma = (const float*)d_in[5];
  const float* beta  = (const float*)d_in[6];
  const float* rmean = (const float*)d_in[7];
  const float* rvar  = (const float*)d_in[8];
  float* out = (float*)d_out;
  float* ws = (float*)d_ws;

  // workspace layout (floats)
  float* y    = ws;                 // 33,554,432
  float* Gp   = y + 33554432;       //  2,097,152
  float* sxq  = Gp + 2097152;       //     32,768
  float* sxk  = sxq + 32768;        //     32,768
  float* M1   = sxk + 32768;        //    524,288
  float* pbv1 = M1 + 524288;        //      8,192
  float* G2   = pbv1 + 8192;        //     65,536
  float* sq2  = G2 + 65536;         //      8,192
  float* sk2  = sq2 + 8192;         //      8,192
  float* M2   = sk2 + 8192;         //     65,536
  float* pbv2 = M2 + 65536;         //      8,192
  size_t need = (size_t)36405248 * sizeof(float);
  if (ws_size < need) return;  // fail validation cleanly rather than corrupt

  k1_gram<<<512, 256, 0, stream>>>(x, Gp, sxq, sxk);
  k2_attn1<<<128, 256, 0, stream>>>(w1, b1, Gp, sxq, sxk, M1, pbv1);
  k3_out1<<<512, 256, 0, stream>>>(x, M1, pbv1, gamma, beta, rmean, rvar, y);
  k4_gram2<<<1024, 256, 0, stream>>>(y, G2, sq2, sk2);
  k5_attn2<<<1024, 64, 0, stream>>>(w2, b2, G2, sq2, sk2, M2, pbv2);
  k6_final<<<1024, 256, 0, stream>>>(y, M2, pbv2, out);
}